// Round 1
// 258.640 us; speedup vs baseline: 1.0564x; 1.0564x over previous
//
#include <hip/hip_runtime.h>
#include <hip/hip_bf16.h>

// Problem constants (from reference)
#define BATCH 2
#define SEQ   2048
#define DMODEL 1024
#define NHEAD 16
#define DK    64
#define MTOK  (BATCH * SEQ)      // 4096 token rows

typedef __attribute__((ext_vector_type(8))) short bf16x8;   // 8 bf16 in 4 VGPRs
typedef __attribute__((ext_vector_type(4))) float f32x4;    // MFMA 16x16 accumulator

// float -> bf16 bits, round-to-nearest-even
__device__ __forceinline__ unsigned short f2bf(float x) {
    unsigned u = __float_as_uint(x);
    u = (u + 0x7FFFu + ((u >> 16) & 1u)) >> 16;
    return (unsigned short)u;
}

__device__ __forceinline__ void store_out(float* p, float v)          { *p = v; }
__device__ __forceinline__ void store_out(unsigned short* p, float v) { *p = f2bf(v); }

// async global->LDS, 16 B per lane; LDS dest = wave-uniform base + lane*16.
// Per-lane SOURCE addresses are arbitrary (gather) — verified rounds 2-5.
__device__ __forceinline__ void g2lds16(const void* g, void* l) {
    __builtin_amdgcn_global_load_lds(
        (const __attribute__((address_space(1))) void*)g,
        (__attribute__((address_space(3))) void*)l, 16, 0, 0);
}

// counted vmem wait: leave N loads in flight (never drain to 0 in main loop)
template <int N>
__device__ __forceinline__ void s_wait_vmcnt() {
    asm volatile("s_waitcnt vmcnt(%0)" :: "n"(N) : "memory");
}
__device__ __forceinline__ void s_wait_lgkm0() {
    asm volatile("s_waitcnt lgkmcnt(0)" ::: "memory");
}
// raw barrier as asm with memory clobber: no compiler-inserted vmcnt(0) drain,
// and no memory op (ds_read / global_load_lds) may be reordered across it.
__device__ __forceinline__ void s_bar() {
    asm volatile("s_barrier" ::: "memory");
}

// ---------------------------------------------------------------------------
// fp32 -> bf16 elementwise convert, 3 tensors in one launch (z selects).
// ---------------------------------------------------------------------------
__global__ __launch_bounds__(256) void cvt3_bf16_kernel(
    const float* __restrict__ s0, const float* __restrict__ s1,
    const float* __restrict__ s2,
    unsigned short* __restrict__ d0, unsigned short* __restrict__ d1,
    unsigned short* __restrict__ d2, int n)
{
    const float* src; unsigned short* dst;
    switch (blockIdx.z) {
        case 0:  src = s0; dst = d0; break;
        case 1:  src = s1; dst = d1; break;
        default: src = s2; dst = d2; break;
    }
    int i = (blockIdx.x * 256 + threadIdx.x) * 8;
    if (i >= n) return;
    float4 a = *(const float4*)(src + i);
    float4 b = *(const float4*)(src + i + 4);
    union { unsigned short s[8]; uint4 u; } o;
    o.s[0] = f2bf(a.x); o.s[1] = f2bf(a.y); o.s[2] = f2bf(a.z); o.s[3] = f2bf(a.w);
    o.s[4] = f2bf(b.x); o.s[5] = f2bf(b.y); o.s[6] = f2bf(b.z); o.s[7] = f2bf(b.w);
    *(uint4*)(dst + i) = o.u;
}

// ---------------------------------------------------------------------------
// Transpose + convert the 4 weight matrices: Wt[n][k] = (bf16)W[k][n], 1024^2.
// ---------------------------------------------------------------------------
__global__ __launch_bounds__(256) void wtrans_kernel(
    const float* __restrict__ w0, const float* __restrict__ w1,
    const float* __restrict__ w2, const float* __restrict__ w3,
    unsigned short* __restrict__ t0, unsigned short* __restrict__ t1,
    unsigned short* __restrict__ t2, unsigned short* __restrict__ t3)
{
    __shared__ float tile[32][33];
    const float* W; unsigned short* T;
    switch (blockIdx.z) {
        case 0:  W = w0; T = t0; break;
        case 1:  W = w1; T = t1; break;
        case 2:  W = w2; T = t2; break;
        default: W = w3; T = t3; break;
    }
    const int n0 = blockIdx.x * 32, k0 = blockIdx.y * 32;
    const int t  = threadIdx.x;
    const int r  = t >> 3;          // 0..31
    const int c4 = (t & 7) * 4;     // 0..28

    float4 v = *(const float4*)&W[(size_t)(k0 + r) * DMODEL + n0 + c4];
    tile[r][c4 + 0] = v.x; tile[r][c4 + 1] = v.y;
    tile[r][c4 + 2] = v.z; tile[r][c4 + 3] = v.w;
    __syncthreads();

    union { unsigned short s[4]; uint2 u; } o;
#pragma unroll
    for (int u = 0; u < 4; ++u) o.s[u] = f2bf(tile[c4 + u][r]);
    *(uint2*)&T[(size_t)(n0 + r) * DMODEL + k0 + c4] = o.u;
}

// ---------------------------------------------------------------------------
// MFMA GEMM: C[M,N] = A[M,K] @ Bt[N,K]^T + bias, scaled (fp32 acc).
// Tile 128 x (NTILE*32), BK=64, fragment-ordered LDS + global_load_lds gather.
//
// Round-7: 2-deep double-buffered pipeline with COUNTED vmcnt (T3/T4 minimum).
// Per K-step: wait vmcnt(PW) (current tile landed; next tile's PW loads stay
// in flight) -> barrier -> ds_read+MFMA -> lgkmcnt(0) -> barrier -> issue
// tile t+2 into the buffer just read. vmcnt never drains to 0 in the loop,
// so global-load latency hides under a full K-step of compute instead of
// being exposed serially every iteration (was: MfmaUtil 11%, all pipes idle).
// ---------------------------------------------------------------------------
struct GemmP {
    const unsigned short* A;
    const unsigned short* Bt;
    const float* bias;
    void* C;
    int N, K, ctShift, biasByRow;
    float scale;
};
struct Gemm3 { GemmP p[3]; };

template <typename OutT, int NTILE>
__global__ __launch_bounds__(256) void gemm_lds_kernel(Gemm3 g)
{
    constexpr int NBLK  = 16 + 4 * NTILE;   // 512-short staging blocks / buffer
    constexpr int BUFSZ = NBLK * 512;       // shorts per buffer
    constexpr int PW    = NBLK / 4;         // staging loads per wave per K-step

    __shared__ unsigned short sS[2][BUFSZ]; // [buf][A: 0..16*512 | B: rest]

    const GemmP p = g.p[blockIdx.z];
    const unsigned short* __restrict__ A  = p.A;
    const unsigned short* __restrict__ Bt = p.Bt;
    OutT* __restrict__ C = (OutT*)p.C;
    const int K = p.K, N = p.N;

    const int bid = blockIdx.x;
    const int bx = bid & ((1 << p.ctShift) - 1);
    const int by = bid >> p.ctShift;
    const int row0 = by * 128;
    const int col0 = bx * (NTILE * 32);

    const int t    = threadIdx.x;
    const int w    = t >> 6;
    const int lane = t & 63;
    const int ln   = lane & 15;
    const int qg   = lane >> 4;
    const int wm   = w >> 1;
    const int wn   = w & 1;

    // wave-uniform staging assignments: blocks [0,16) = A, [16,16+4*NTILE) = B
    const unsigned short* sp[PW];
    unsigned short* lp[PW];
#pragma unroll
    for (int i = 0; i < PW; ++i) {
        const int s = w * PW + i;
        if (s < 16) {
            const int mtg = s >> 1, kc = s & 1;
            sp[i] = A + (size_t)(row0 + mtg * 16 + ln) * K + kc * 32 + qg * 8;
        } else {
            const int bi = s - 16;
            const int ntg = bi >> 1, kc = bi & 1;
            sp[i] = Bt + (size_t)(col0 + ntg * 16 + ln) * K + kc * 32 + qg * 8;
        }
        lp[i] = &sS[0][s * 512];
    }

    f32x4 acc[4][NTILE];
#pragma unroll
    for (int mt = 0; mt < 4; ++mt)
#pragma unroll
        for (int nt = 0; nt < NTILE; ++nt) acc[mt][nt] = (f32x4){0.f, 0.f, 0.f, 0.f};

    const int nt = K / 64;

    // ---- prologue: tiles 0 and 1 in flight ----
#pragma unroll
    for (int i = 0; i < PW; ++i) g2lds16(sp[i], lp[i]);
    if (nt > 1) {
#pragma unroll
        for (int i = 0; i < PW; ++i) g2lds16(sp[i] + 64, lp[i] + BUFSZ);
    }

    int cur = 0;
    for (int kt = 0; kt < nt; ++kt) {
        // current tile's PW loads are the oldest; leave the next PW in flight
        if (kt < nt - 1) s_wait_vmcnt<PW>();
        else             s_wait_vmcnt<0>();
        s_bar();

        const unsigned short* bufA = &sS[cur][0];
        const unsigned short* bufB = &sS[cur][16 * 512];
#pragma unroll
        for (int kc = 0; kc < 2; ++kc) {
            bf16x8 aF[4], bF[NTILE];
#pragma unroll
            for (int mt = 0; mt < 4; ++mt)
                aF[mt] = *(const bf16x8*)&bufA[(((wm * 4 + mt) * 2) + kc) * 512 + lane * 8];
#pragma unroll
            for (int n2 = 0; n2 < NTILE; ++n2)
                bF[n2] = *(const bf16x8*)&bufB[(((wn * NTILE + n2) * 2) + kc) * 512 + lane * 8];
#pragma unroll
            for (int mt = 0; mt < 4; ++mt)
#pragma unroll
                for (int n2 = 0; n2 < NTILE; ++n2)
                    acc[mt][n2] = __builtin_amdgcn_mfma_f32_16x16x32_bf16(
                        aF[mt], bF[n2], acc[mt][n2], 0, 0, 0);
        }

        // all of this wave's ds_reads must be COMPLETE (not just issued)
        // before anyone overwrites buf[cur] with tile kt+2
        s_wait_lgkm0();
        s_bar();

        if (kt + 2 < nt) {
            const int koff = (kt + 2) * 64;
#pragma unroll
            for (int i = 0; i < PW; ++i)
                g2lds16(sp[i] + koff, lp[i] + cur * BUFSZ);
        }
        cur ^= 1;
    }

    float bcol[NTILE], brow[4][4];
    if (!p.biasByRow) {
#pragma unroll
        for (int n2 = 0; n2 < NTILE; ++n2)
            bcol[n2] = p.bias[col0 + wn * NTILE * 16 + n2 * 16 + ln];
    } else {
#pragma unroll
        for (int mt = 0; mt < 4; ++mt)
#pragma unroll
            for (int r = 0; r < 4; ++r)
                brow[mt][r] = p.bias[row0 + wm * 64 + mt * 16 + qg * 4 + r];
    }

#pragma unroll
    for (int mt = 0; mt < 4; ++mt)
#pragma unroll
        for (int n2 = 0; n2 < NTILE; ++n2)
#pragma unroll
            for (int r = 0; r < 4; ++r) {
                int row = row0 + wm * 64 + mt * 16 + qg * 4 + r;
                int col = col0 + wn * NTILE * 16 + n2 * 16 + ln;
                float bb = p.biasByRow ? brow[mt][r] : bcol[n2];
                store_out(&C[(size_t)row * N + col], (acc[mt][n2][r] + bb) * p.scale);
            }
}

// ---------------------------------------------------------------------------
// Flash attention, round-6 structure (unchanged this round):
//  - Q, K, V all staged fragment-ordered via global_load_lds (V comes from the
//    transposed projection VT[d][token] -> contiguous 16B per lane, no LDS
//    transpose, no scalar writes)
//  - double-buffered K/V: prefetch tile j+1 before computing tile j; ONE
//    barrier per tile, with the vmcnt drain overlapped by a full tile of work
//  - l (softmax denom) via MFMA row-sum against an all-ones B fragment
//  - scores arrive pre-scaled by 0.125*log2e (folded into Q projection) ->
//    softmax runs in exp2 domain with zero scale multiplies
// ---------------------------------------------------------------------------
#define BR 64
#define BC 64
#define PSTR 72

__global__ __launch_bounds__(256) void attn_mfma_kernel(
    const unsigned short* __restrict__ Qg, const unsigned short* __restrict__ Kg,
    const unsigned short* __restrict__ VT, unsigned short* __restrict__ O)
{
    __shared__ unsigned short sK[2][8 * 512];   // 16 KB
    __shared__ unsigned short sV[2][8 * 512];   // 16 KB
    __shared__ unsigned short sQ[8 * 512];      // 8 KB
    __shared__ unsigned short sP[BR * PSTR];    // 9 KB

    const int t    = threadIdx.x;
    const int w    = t >> 6;
    const int lane = t & 63;
    const int ln   = lane & 15;
    const int qg   = lane >> 4;

    const int id  = blockIdx.x;
    const int bh  = id & 31;
    const int qt  = (SEQ / BR - 1) - (id >> 5);   // heavy tiles first
    const int b   = bh >> 4;
    const int h   = bh & 15;
    const int qi0 = qt * BR;

    const size_t rowbase = (size_t)b * SEQ;
    const size_t colbase = (size_t)h * DK;

    // ---- stage Q + K/V tile 0 (buf 0) ----
#pragma unroll
    for (int i = 0; i < 2; ++i) {
        const int s = w * 2 + i;
        const int nt = s >> 1, kc = s & 1;
        g2lds16(Qg + (rowbase + qi0 + w * 16 + ln) * DMODEL + colbase + i * 32 + qg * 8,
                &sQ[s * 512]);
        g2lds16(Kg + (rowbase + nt * 16 + ln) * DMODEL + colbase + kc * 32 + qg * 8,
                &sK[0][s * 512]);
        g2lds16(VT + (size_t)(colbase + nt * 16 + ln) * MTOK + rowbase + kc * 32 + qg * 8,
                &sV[0][s * 512]);
    }
    __syncthreads();

    bf16x8 aq[2];
#pragma unroll
    for (int kc = 0; kc < 2; ++kc)
        aq[kc] = *(const bf16x8*)&sQ[(w * 2 + kc) * 512 + lane * 8];

    const short one_bf = (short)0x3F80;
    const bf16x8 bone = (bf16x8){one_bf, one_bf, one_bf, one_bf,
                                 one_bf, one_bf, one_bf, one_bf};

    f32x4 ofrag[4];
#pragma unroll
    for (int nt = 0; nt < 4; ++nt) ofrag[nt] = (f32x4){0.f, 0.f, 0.f, 0.f};
    f32x4 osum = (f32x4){0.f, 0.f, 0.f, 0.f};
    float m_r[4];
#pragma unroll
    for (int r = 0; r < 4; ++r) m_r[r] = -3.0e38f;

    const int ntiles = qt + 1;
    for (int jt = 0; jt < ntiles; ++jt) {
        const int cur = jt & 1;

        // ---- prefetch tile jt+1 into the alternate buffer (latency hidden
        //      behind this tile's compute; drained at the end barrier) ----
        if (jt + 1 < ntiles) {
            const int j1 = (jt + 1) * BC;
            const int nb = cur ^ 1;
#pragma unroll
            for (int i = 0; i < 2; ++i) {
                const int s = w * 2 + i;
                const int nt = s >> 1, kc = s & 1;
                g2lds16(Kg + (rowbase + j1 + nt * 16 + ln) * DMODEL + colbase + kc * 32 + qg * 8,
                        &sK[nb][s * 512]);
                g2lds16(VT + (size_t)(colbase + nt * 16 + ln) * MTOK + rowbase + j1 + kc * 32 + qg * 8,
                        &sV[nb][s * 512]);
            }
        }

        // ---- S = Q K^T (scores pre-scaled by 0.125*log2e) ----
        f32x4 sf[4];
#pragma unroll
        for (int nt = 0; nt < 4; ++nt) {
            f32x4 a2 = (f32x4){0.f, 0.f, 0.f, 0.f};
#pragma unroll
            for (int kc = 0; kc < 2; ++kc) {
                bf16x8 bk = *(const bf16x8*)&sK[cur][(nt * 2 + kc) * 512 + lane * 8];
                a2 = __builtin_amdgcn_mfma_f32_16x16x32_bf16(aq[kc], bk, a2, 0, 0, 0);
            }
            sf[nt] = a2;
        }

        // ---- causal mask (diagonal tile only) ----
        if (jt == ntiles - 1) {
#pragma unroll
            for (int nt = 0; nt < 4; ++nt)
#pragma unroll
                for (int r = 0; r < 4; ++r) {
                    int qrow = w * 16 + qg * 4 + r;
                    int col  = nt * 16 + ln;
                    if (col > qrow) sf[nt][r] = -1.0e30f;
                }
        }

        // ---- online softmax (exp2 domain); l via MFMA row-sum below ----
        float rmax[4];
#pragma unroll
        for (int r = 0; r < 4; ++r)
            rmax[r] = fmaxf(fmaxf(sf[0][r], sf[1][r]), fmaxf(sf[2][r], sf[3][r]));
#pragma unroll
        for (int off = 8; off >= 1; off >>= 1)
#pragma unroll
            for (int r = 0; r < 4; ++r)
                rmax[r] = fmaxf(rmax[r], __shfl_xor(rmax[r], off));

        float alpha[4];
#pragma unroll
        for (int r = 0; r < 4; ++r) {
            float mn = fmaxf(m_r[r], rmax[r]);
            alpha[r] = exp2f(m_r[r] - mn);
            m_r[r] = mn;
        }

#pragma unroll
        for (int nt = 0; nt < 4; ++nt)
#pragma unroll
            for (int r = 0; r < 4; ++r) {
                float pv = exp2f(sf[nt][r] - m_r[r]);
                int row = w * 16 + qg * 4 + r;
                int col = (nt * 16 + ln) ^ (((w * 4 + qg) & 7) * 8);
                sP[row * PSTR + col] = f2bf(pv);
            }

#pragma unroll
        for (int nt = 0; nt < 4; ++nt)
#pragma unroll
            for (int r = 0; r < 4; ++r) ofrag[nt][r] *= alpha[r];
#pragma unroll
        for (int r = 0; r < 4; ++r) osum[r] *= alpha[r];

        // ---- P back as A-fragments ----
        bf16x8 apf[2];
#pragma unroll
        for (int kc = 0; kc < 2; ++kc) {
            int row = w * 16 + ln;
            int col = (kc * 32 + qg * 8) ^ ((((row >> 2) & 7)) * 8);
            apf[kc] = *(const bf16x8*)&sP[row * PSTR + col];
        }

        // ---- O += P V ; l += P . ones (MFMA row-sum) ----
#pragma unroll
        for (int kc = 0; kc < 2; ++kc)
            osum = __builtin_amdgcn_mfma_f32_16x16x32_bf16(apf[kc], bone, osum, 0, 0, 0);
#pragma unroll
        for (int nt = 0; nt < 4; ++nt) {
#pragma unroll
            for (int kc = 0; kc < 2; ++kc) {
                bf16x8 bv = *(const bf16x8*)&sV[cur][(nt * 2 + kc) * 512 + lane * 8];
                ofrag[nt] = __builtin_amdgcn_mfma_f32_16x16x32_bf16(apf[kc], bv, ofrag[nt], 0, 0, 0);
            }
        }

        __syncthreads();    // publish prefetched tile; protect cur for overwrite
    }

    // ---- epilogue: normalize, write bf16 ctx in [B,S,D] layout ----
    float inv[4];
#pragma unroll
    for (int r = 0; r < 4; ++r) inv[r] = 1.0f / osum[r];
#pragma unroll
    for (int nt = 0; nt < 4; ++nt)
#pragma unroll
        for (int r = 0; r < 4; ++r) {
            int gq = qi0 + w * 16 + qg * 4 + r;
            O[(rowbase + gq) * DMODEL + colbase + nt * 16 + ln] =
                f2bf(ofrag[nt][r] * inv[r]);
        }
}

// ---------------------------------------------------------------------------
extern "C" void kernel_launch(void* const* d_in, const int* in_sizes, int n_in,
                              void* d_out, int out_size, void* d_ws, size_t ws_size,
                              hipStream_t stream)
{
    const float* q  = (const float*)d_in[0];
    const float* k  = (const float*)d_in[1];
    const float* v  = (const float*)d_in[2];
    // d_in[3] = mask (int32 tril) — causality applied analytically (j<=i).
    const float* wq = (const float*)d_in[4];
    const float* bq = (const float*)d_in[5];
    const float* wk = (const float*)d_in[6];
    const float* bk = (const float*)d_in[7];
    const float* wv = (const float*)d_in[8];
    const float* bv = (const float*)d_in[9];
    const float* wo = (const float*)d_in[10];
    const float* bo = (const float*)d_in[11];
    float* out = (float*)d_out;

    const size_t mat  = (size_t)MTOK * DMODEL;     // 4M elements
    const size_t wmat = (size_t)DMODEL * DMODEL;   // 1M elements
    unsigned short* Abq = (unsigned short*)d_ws;   // bf16 activations
    unsigned short* Abk = Abq + mat;
    unsigned short* Abv = Abk + mat;
    unsigned short* WtQ = Abv + mat;               // bf16 transposed weights
    unsigned short* WtK = WtQ + wmat;
    unsigned short* WtV = WtK + wmat;
    unsigned short* WtO = WtV + wmat;
    unsigned short* Qb  = WtO + wmat;              // bf16 Q proj (pre-scaled)
    unsigned short* Kb  = Qb + mat;                // bf16 K proj
    unsigned short* VT  = Kb + mat;                // bf16 V proj, TRANSPOSED [D][MTOK]
    unsigned short* CTX = VT + mat;                // bf16 attention output

    cvt3_bf16_kernel<<<dim3((unsigned)(mat / 2048), 1, 3), 256, 0, stream>>>(
        q, k, v, Abq, Abk, Abv, (int)mat);
    wtrans_kernel<<<dim3(32, 32, 4), 256, 0, stream>>>(wq, wk, wv, wo, WtQ, WtK, WtV, WtO);

    // fused projections: z0=Q (pre-scaled by 0.125*log2e), z1=K, z2=V transposed
    const float qscale = 0.125f * 1.44269504088896f;
    Gemm3 g;
    g.p[0] = (GemmP){Abq, WtQ, bq, (void*)Qb, DMODEL, DMODEL, 3, 0, qscale};
    g.p[1] = (GemmP){Abk, WtK, bk, (void*)Kb, DMODEL, DMODEL, 3, 0, 1.0f};
    g.p[2] = (GemmP){WtV, Abv, bv, (void*)VT, MTOK,   DMODEL, 5, 1, 1.0f};  // swapped operands
    gemm_lds_kernel<unsigned short, 4><<<dim3(256, 1, 3), 256, 0, stream>>>(g);

    attn_mfma_kernel<<<BATCH * NHEAD * (SEQ / BR), 256, 0, stream>>>(Qb, Kb, VT, CTX);

    // output projection: tile 128x64 -> 512 blocks (2/CU)
    Gemm3 go;
    go.p[0] = (GemmP){CTX, WtO, bo, (void*)out, DMODEL, DMODEL, 4, 0, 1.0f};
    go.p[1] = go.p[0];
    go.p[2] = go.p[0];
    gemm_lds_kernel<float, 2><<<dim3(512, 1, 1), 256, 0, stream>>>(go);
}